// Round 6
// baseline (290.216 us; speedup 1.0000x reference)
//
#include <hip/hip_runtime.h>
#include <hip/hip_bf16.h>
#include <math.h>

#define T_LEN 20000
#define HID 150

typedef __attribute__((ext_vector_type(8))) __bf16 bf16x8;
typedef __attribute__((ext_vector_type(4))) float f32x4;

__device__ __forceinline__ short f2bf(float f) {
    unsigned u = __float_as_uint(f);
    u = (u + 0x7fff + ((u >> 16) & 1)) >> 16;
    return (short)u;
}

__device__ __forceinline__ unsigned pk2(float a, float b) {
    __hip_bfloat162 h = __float22bfloat162_rn(make_float2(a, b));
    return *(unsigned*)&h;
}

__device__ __forceinline__ bf16x8 cvt8(float4 a, float4 b) {
    union { unsigned u[4]; bf16x8 v; } r;
    r.u[0] = pk2(a.x, a.y);
    r.u[1] = pk2(a.z, a.w);
    r.u[2] = pk2(b.x, b.y);
    r.u[3] = pk2(b.z, b.w);
    return r.v;
}

// ---------------------------------------------------------------------------
// wprep: bf16 transposed weights. Layout (shorts):
//   [0,66560)        Bt0 [160][416]  sc_W1 rows   0..399  (U)
//   [66560,133120)   Bt1 [160][416]  sc_W1 rows 400..799  (V)
//   [133120,199680)  At1 [160][416]  attn_W1              (X1)
//   [199680,266240)  Bt2 [160][416]  sc_W1 rows 800..1099 (P, K=300)
//   [266240,291840)  At2 [160][160]  attn_W2
//   [291840,318720)  W2t [160][168]  sc_W2
// ---------------------------------------------------------------------------
__global__ __launch_bounds__(256) void wprep(
    const float* __restrict__ sc_W1, const float* __restrict__ attn_W1,
    const float* __restrict__ attn_W2, const float* __restrict__ sc_W2,
    short* __restrict__ wbf)
{
    int t = blockIdx.x * 256 + threadIdx.x;
    if (t >= 318720) return;
    float v = 0.f;
    if (t < 133120) {
        int y = t / 66560, r = t - y * 66560;
        int nn = r / 416, k = r - nn * 416;
        if (nn < HID && k < 400) v = sc_W1[(long)(y * 400 + k) * HID + nn];
    } else if (t < 199680) {
        int r = t - 133120;
        int nn = r / 416, k = r - nn * 416;
        if (nn < HID && k < 400) v = attn_W1[(long)k * HID + nn];
    } else if (t < 266240) {
        int r = t - 199680;
        int nn = r / 416, k = r - nn * 416;
        if (nn < HID && k < 300) v = sc_W1[(long)(800 + k) * HID + nn];
    } else if (t < 291840) {
        int r = t - 266240;
        int nn = r / 160, k = r - nn * 160;
        if (nn < HID && k < HID) v = attn_W2[(long)k * HID + nn];
    } else {
        int r = t - 291840;
        int nn = r / 168, k = r - nn * 168;
        if (nn < HID && k < HID) v = sc_W2[(long)k * HID + nn];
    }
    wbf[t] = f2bf(v);
}

// ---------------------------------------------------------------------------
// fusedA: 16 rows/block, grid 1250. One states pass -> U, V (fp32 stride 160)
// + X1 (LDS bf16) + attn layers 2/3 -> logits.
// The 30 output n-tiles are SPLIT ACROSS WAVES (8/8/7/7): wave w owns tiles
// nt = 4t+w. All waves share the same 16 A-rows (L1-hit). Tail: layer-2 tiles
// split 3/3/2/2, cross-wave reduce through LDS.
// ---------------------------------------------------------------------------
__global__ __launch_bounds__(256) void fusedA(
    const float* __restrict__ states, const short* __restrict__ wbf,
    const float* __restrict__ scb1, const float* __restrict__ ab1,
    const float* __restrict__ ab2, const float* __restrict__ aW3,
    const float* __restrict__ ab3,
    float* __restrict__ U, float* __restrict__ V, float* __restrict__ logits)
{
    __shared__ short h1s[16 * 168];
    __shared__ float red[16][4];
    const int tid = threadIdx.x;
    const int w = tid >> 6, lane = tid & 63;
    const int ml = lane & 15, kg = lane >> 4;
    const int m0 = blockIdx.x * 16;          // 1250 * 16 = 20000 exact

    const float* Arow = states + (long)(m0 + ml) * 400;
    const int nT = (w < 2) ? 8 : 7;

    f32x4 acc[8];
    #pragma unroll
    for (int t = 0; t < 8; ++t) acc[t] = (f32x4){0.f, 0.f, 0.f, 0.f};

    for (int ks = 0; ks < 13; ++ks) {
        int k = ks * 32 + kg * 8;
        float4 a0 = make_float4(0.f, 0.f, 0.f, 0.f);
        float4 a1 = make_float4(0.f, 0.f, 0.f, 0.f);
        if (k + 4 <= 400) a0 = *(const float4*)&Arow[k];
        if (k + 8 <= 400) a1 = *(const float4*)&Arow[k + 4];
        bf16x8 af = cvt8(a0, a1);
        #pragma unroll
        for (int t = 0; t < 8; ++t) {
            if (t < nT) {
                int nt = 4 * t + w;
                bf16x8 bf = *(const bf16x8*)&wbf[(long)(nt * 16 + ml) * 416 + k];
                acc[t] = __builtin_amdgcn_mfma_f32_16x16x32_bf16(af, bf, acc[t], 0, 0, 0);
            }
        }
    }

    #pragma unroll
    for (int t = 0; t < 8; ++t) {
        if (t < nT) {
            int nt = 4 * t + w;
            if (nt < 10) {
                int col = nt * 16 + ml;
                float bv = (col < HID) ? scb1[col] : 0.f;
                #pragma unroll
                for (int r = 0; r < 4; ++r) {
                    int gm = m0 + kg * 4 + r;
                    U[(long)gm * 160 + col] = (col < HID) ? acc[t][r] + bv : 0.f;
                }
            } else if (nt < 20) {
                int col = (nt - 10) * 16 + ml;
                #pragma unroll
                for (int r = 0; r < 4; ++r) {
                    int gm = m0 + kg * 4 + r;
                    V[(long)gm * 160 + col] = (col < HID) ? acc[t][r] : 0.f;
                }
            } else {
                int col = (nt - 20) * 16 + ml;
                float bv = (col < HID) ? ab1[col] : 0.f;
                #pragma unroll
                for (int r = 0; r < 4; ++r) {
                    int row = kg * 4 + r;
                    float v = (col < HID) ? fmaxf(acc[t][r] + bv, 0.f) : 0.f;
                    h1s[row * 168 + col] = f2bf(v);
                }
            }
        }
    }
    __syncthreads();

    // attn layer 2 (K=160) tiles split 3/3/2/2 + relu-dot-W3 epilogue
    const short* At2 = wbf + 266240;
    bf16x8 af2[5];
    #pragma unroll
    for (int ks = 0; ks < 5; ++ks)
        af2[ks] = *(const bf16x8*)&h1s[ml * 168 + ks * 32 + kg * 8];

    const int nT2 = (w < 2) ? 3 : 2;
    float score[4] = {0.f, 0.f, 0.f, 0.f};
    #pragma unroll
    for (int t = 0; t < 3; ++t) {
        if (t < nT2) {
            int nt = 4 * t + w;
            f32x4 a2 = {0.f, 0.f, 0.f, 0.f};
            #pragma unroll
            for (int ks = 0; ks < 5; ++ks) {
                bf16x8 bf = *(const bf16x8*)&At2[(long)(nt * 16 + ml) * 160 + ks * 32 + kg * 8];
                a2 = __builtin_amdgcn_mfma_f32_16x16x32_bf16(af2[ks], bf, a2, 0, 0, 0);
            }
            int col = nt * 16 + ml;
            float b2v = (col < HID) ? ab2[col] : 0.f;
            float w3v = (col < HID) ? aW3[col] : 0.f;
            #pragma unroll
            for (int r = 0; r < 4; ++r)
                score[r] += fmaxf(a2[r] + b2v, 0.f) * w3v;
        }
    }
    #pragma unroll
    for (int r = 0; r < 4; ++r) {
        score[r] += __shfl_xor(score[r], 1);
        score[r] += __shfl_xor(score[r], 2);
        score[r] += __shfl_xor(score[r], 4);
        score[r] += __shfl_xor(score[r], 8);
    }
    if (ml == 0) {
        #pragma unroll
        for (int r = 0; r < 4; ++r) red[kg * 4 + r][w] = score[r];
    }
    __syncthreads();
    if (tid < 16)
        logits[m0 + tid] = red[tid][0] + red[tid][1] + red[tid][2] + red[tid][3] + ab3[0];
}

// ---------------------------------------------------------------------------
// pkern: P = embeds @ sc_W1[800:1100] (K=300). 16 rows/block, grid 1250,
// 10 n-tiles split 3/3/2/2 across waves.
// ---------------------------------------------------------------------------
__global__ __launch_bounds__(256) void pkern(
    const float* __restrict__ embeds, const short* __restrict__ wbf,
    float* __restrict__ P)
{
    const int tid = threadIdx.x;
    const int w = tid >> 6, lane = tid & 63;
    const int ml = lane & 15, kg = lane >> 4;
    const int m0 = blockIdx.x * 16;
    const short* Bt = wbf + 199680;

    const float* Arow = embeds + (long)(m0 + ml) * 300;
    const int nT = (w < 2) ? 3 : 2;

    f32x4 acc[3];
    #pragma unroll
    for (int t = 0; t < 3; ++t) acc[t] = (f32x4){0.f, 0.f, 0.f, 0.f};

    for (int ks = 0; ks < 10; ++ks) {
        int k = ks * 32 + kg * 8;
        float4 a0 = make_float4(0.f, 0.f, 0.f, 0.f);
        float4 a1 = make_float4(0.f, 0.f, 0.f, 0.f);
        if (k + 4 <= 300) a0 = *(const float4*)&Arow[k];
        if (k + 8 <= 300) a1 = *(const float4*)&Arow[k + 4];
        bf16x8 af = cvt8(a0, a1);
        #pragma unroll
        for (int t = 0; t < 3; ++t) {
            if (t < nT) {
                int nt = 4 * t + w;
                bf16x8 bf = *(const bf16x8*)&Bt[(long)(nt * 16 + ml) * 416 + k];
                acc[t] = __builtin_amdgcn_mfma_f32_16x16x32_bf16(af, bf, acc[t], 0, 0, 0);
            }
        }
    }

    #pragma unroll
    for (int t = 0; t < 3; ++t) {
        if (t < nT) {
            int nt = 4 * t + w;
            int col = nt * 16 + ml;
            #pragma unroll
            for (int r = 0; r < 4; ++r) {
                int gm = m0 + kg * 4 + r;
                P[(long)gm * 160 + col] = (col < HID) ? acc[t][r] : 0.f;
            }
        }
    }
}

// ---------------------------------------------------------------------------
// span_all: grid (313, 4). Block (x,y) handles chunk x (64 spans) for widths
// n in {1-3, 4-5, 6-8, 9-10}[y]. Chunk-max softmax makes pooling incremental
// in n; y>0 blocks re-derive the prefix (<=8 redundant L2-hit P rows).
// Phase 2: 16x16x32 MFMA vs W2t straight from global (L2-resident).
// ---------------------------------------------------------------------------
__global__ __launch_bounds__(256) void span_all(
    const float* __restrict__ U, const float* __restrict__ V,
    const float* __restrict__ Pb, const float* __restrict__ logits,
    const short* __restrict__ W2t, const float* __restrict__ b2,
    const float* __restrict__ W3, const float* __restrict__ b3,
    float* __restrict__ out)
{
    __shared__ short h1s[64 * 168];    // 21504 B
    __shared__ float Ls[73];
    __shared__ float ebuf[73];

    const int tid = threadIdx.x;
    const int s0 = blockIdx.x * 64;
    const int y = blockIdx.y;
    const int nlo = (y == 0) ? 1 : (y == 1) ? 4 : (y == 2) ? 6 : 9;
    const int nhi = (y == 0) ? 3 : (y == 1) ? 5 : (y == 2) ? 8 : 10;

    if (tid < 73) {
        int r = s0 + tid; if (r > T_LEN - 1) r = T_LEN - 1;
        Ls[tid] = logits[r];
    }
    __syncthreads();
    if (tid < 73) {
        float M = -1e30f;
        for (int t = 0; t < 73; ++t) M = fmaxf(M, Ls[t]);
        ebuf[tid] = expf(Ls[tid] - M);
    }
    __syncthreads();

    const int i = tid >> 2;       // span within chunk
    const int q = tid & 3;        // dim quarter [40q, 40q+40)
    const int s = s0 + i;
    int su = s; if (su > T_LEN - 1) su = T_LEN - 1;

    float4 Ur[10];
    {
        const float4* U4 = (const float4*)(U + (long)su * 160) + q * 10;
        #pragma unroll
        for (int p = 0; p < 10; ++p) Ur[p] = U4[p];
    }
    float accp[40];
    #pragma unroll
    for (int d = 0; d < 40; ++d) accp[d] = 0.f;
    float den = 0.f;

    // prefix j = 0..nlo-2
    for (int j = 0; j < nlo - 1; ++j) {
        int r = s + j; if (r > T_LEN - 1) r = T_LEN - 1;
        float e = ebuf[i + j];
        den += e;
        const float4* Pr = (const float4*)(Pb + (long)r * 160) + q * 10;
        #pragma unroll
        for (int p = 0; p < 10; ++p) {
            float4 pv = Pr[p];
            accp[4 * p + 0] += e * pv.x;
            accp[4 * p + 1] += e * pv.y;
            accp[4 * p + 2] += e * pv.z;
            accp[4 * p + 3] += e * pv.w;
        }
    }

    const int w = tid >> 6, lane = tid & 63;
    const int ml = lane & 15, kg = lane >> 4;

    for (int n = nlo; n <= nhi; ++n) {
        int r = s + n - 1; if (r > T_LEN - 1) r = T_LEN - 1;
        float e = ebuf[i + n - 1];
        den += e;
        {
            const float4* Pr = (const float4*)(Pb + (long)r * 160) + q * 10;
            #pragma unroll
            for (int p = 0; p < 10; ++p) {
                float4 pv = Pr[p];
                accp[4 * p + 0] += e * pv.x;
                accp[4 * p + 1] += e * pv.y;
                accp[4 * p + 2] += e * pv.z;
                accp[4 * p + 3] += e * pv.w;
            }
        }
        float invd = 1.f / den;
        {
            const float4* Vr = (const float4*)(V + (long)r * 160) + q * 10;
            #pragma unroll
            for (int p = 0; p < 10; ++p) {
                float4 vv = Vr[p];
                float x0 = fmaxf(Ur[p].x + vv.x + accp[4 * p + 0] * invd, 0.f);
                float x1 = fmaxf(Ur[p].y + vv.y + accp[4 * p + 1] * invd, 0.f);
                float x2 = fmaxf(Ur[p].z + vv.z + accp[4 * p + 2] * invd, 0.f);
                float x3 = fmaxf(Ur[p].w + vv.w + accp[4 * p + 3] * invd, 0.f);
                *(uint2*)&h1s[i * 168 + 40 * q + 4 * p] =
                    make_uint2(pk2(x0, x1), pk2(x2, x3));
            }
        }
        __syncthreads();

        bf16x8 af[5];
        #pragma unroll
        for (int ks = 0; ks < 5; ++ks)
            af[ks] = *(const bf16x8*)&h1s[(16 * w + ml) * 168 + ks * 32 + kg * 8];

        float score[4] = {0.f, 0.f, 0.f, 0.f};
        #pragma unroll
        for (int nt = 0; nt < 10; ++nt) {
            f32x4 am = {0.f, 0.f, 0.f, 0.f};
            #pragma unroll
            for (int ks = 0; ks < 5; ++ks) {
                bf16x8 bf = *(const bf16x8*)&W2t[(long)(nt * 16 + ml) * 168 + ks * 32 + kg * 8];
                am = __builtin_amdgcn_mfma_f32_16x16x32_bf16(af[ks], bf, am, 0, 0, 0);
            }
            int col = nt * 16 + ml;
            float b2v = (col < HID) ? b2[col] : 0.f;
            float w3v = (col < HID) ? W3[col] : 0.f;
            #pragma unroll
            for (int rr = 0; rr < 4; ++rr)
                score[rr] += fmaxf(am[rr] + b2v, 0.f) * w3v;
        }
        #pragma unroll
        for (int rr = 0; rr < 4; ++rr) {
            score[rr] += __shfl_xor(score[rr], 1);
            score[rr] += __shfl_xor(score[rr], 2);
            score[rr] += __shfl_xor(score[rr], 4);
            score[rr] += __shfl_xor(score[rr], 8);
        }
        if (ml == 0) {
            const int S = T_LEN - n + 1;
            const int out_off = (n - 1) * (T_LEN + 1) - (n - 1) * n / 2;
            float bb = b3[0];
            #pragma unroll
            for (int rr = 0; rr < 4; ++rr) {
                int sr = s0 + 16 * w + kg * 4 + rr;
                if (sr < S) out[out_off + sr] = score[rr] + bb;
            }
        }
        __syncthreads();
    }
}

// ---------------------------------------------------------------------------
extern "C" void kernel_launch(void* const* d_in, const int* in_sizes, int n_in,
                              void* d_out, int out_size, void* d_ws, size_t ws_size,
                              hipStream_t stream) {
    const float* embeds  = (const float*)d_in[0];
    const float* states  = (const float*)d_in[1];
    const float* attn_W1 = (const float*)d_in[2];
    const float* attn_b1 = (const float*)d_in[3];
    const float* attn_W2 = (const float*)d_in[4];
    const float* attn_b2 = (const float*)d_in[5];
    const float* attn_W3 = (const float*)d_in[6];
    const float* attn_b3 = (const float*)d_in[7];
    const float* sc_W1   = (const float*)d_in[8];
    const float* sc_b1   = (const float*)d_in[9];
    const float* sc_W2   = (const float*)d_in[10];
    const float* sc_b2   = (const float*)d_in[11];
    const float* sc_W3   = (const float*)d_in[12];
    const float* sc_b3   = (const float*)d_in[13];
    float* out = (float*)d_out;

    float* ws = (float*)d_ws;
    float* Ubuf   = ws;                     // [20000][160] fp32
    float* Vbuf   = ws + 3200000;
    float* Pbuf   = ws + 6400000;
    float* logits = ws + 9600000;           // 20,000
    short* wbf    = (short*)(ws + 9620000); // 318,720 shorts

    wprep<<<1245, 256, 0, stream>>>(sc_W1, attn_W1, attn_W2, sc_W2, wbf);
    fusedA<<<1250, 256, 0, stream>>>(states, wbf, sc_b1, attn_b1,
                                     attn_b2, attn_W3, attn_b3,
                                     Ubuf, Vbuf, logits);
    pkern<<<1250, 256, 0, stream>>>(embeds, wbf, Pbuf);
    span_all<<<dim3(313, 4), 256, 0, stream>>>(Ubuf, Vbuf, Pbuf, logits,
                                               wbf + 291840, sc_b2, sc_W3, sc_b3,
                                               out);
}